// Round 11
// baseline (236.872 us; speedup 1.0000x reference)
//
#include <hip/hip_runtime.h>
#include <hip/hip_bf16.h>
#include <stdint.h>

typedef __bf16 bf16;
typedef __attribute__((ext_vector_type(8))) __bf16 bf16x8;
typedef __attribute__((ext_vector_type(4))) float f32x4;
typedef __attribute__((ext_vector_type(16))) float f32x16;

#define SEQ   2048
#define HEADS 8
#define CDIM  512
// C2 = SCALE * log2(e) = 0.125 * 1.4426950408889634
#define C2 0.18033688011112043f

__device__ __forceinline__ void glds16(const bf16* g, bf16* l) {
    __builtin_amdgcn_global_load_lds((const __attribute__((address_space(1))) void*)g,
                                     (__attribute__((address_space(3))) void*)l, 16, 0, 0);
}
__device__ __forceinline__ uint32_t pk_bf16(float a, float b) {
    uint32_t r; asm("v_cvt_pk_bf16_f32 %0, %1, %2" : "=v"(r) : "v"(a), "v"(b)); return r;
}
__device__ __forceinline__ void pl_swap(uint32_t &a, uint32_t &b) {
    asm("v_permlane32_swap_b32 %0, %1" : "+v"(a), "+v"(b));
}
__device__ __forceinline__ void wait_vm4() { asm volatile("s_waitcnt vmcnt(4)" ::: "memory"); }
__device__ __forceinline__ void wait_vm3() { asm volatile("s_waitcnt vmcnt(3)" ::: "memory"); }
__device__ __forceinline__ void wait_vm0() { asm volatile("s_waitcnt vmcnt(0)" ::: "memory"); }

// ---------------------------------------------------------------------------
// 1) hs fp32 -> bf16
__global__ __launch_bounds__(256) void k_cvt_hs(const float* __restrict__ in,
                                                bf16* __restrict__ out) {
    int idx = blockIdx.x * 256 + threadIdx.x;
    const float4* in4 = reinterpret_cast<const float4*>(in);
    float4 a = in4[idx * 2], b = in4[idx * 2 + 1];
    bf16x8 o;
    o[0] = (bf16)a.x; o[1] = (bf16)a.y; o[2] = (bf16)a.z; o[3] = (bf16)a.w;
    o[4] = (bf16)b.x; o[5] = (bf16)b.y; o[6] = (bf16)b.z; o[7] = (bf16)b.w;
    reinterpret_cast<bf16x8*>(out)[idx] = o;
}

// ---------------------------------------------------------------------------
// 2) weight transpose+convert: W[fin][fout] f32 -> Wt[fout][fin] bf16 (4 mats)
__global__ __launch_bounds__(256) void k_wtrans(const float* __restrict__ w0,
                                                const float* __restrict__ w1,
                                                const float* __restrict__ w2,
                                                const float* __restrict__ w3,
                                                bf16* __restrict__ wt) {
    const float* w = blockIdx.z == 0 ? w0 : blockIdx.z == 1 ? w1 : blockIdx.z == 2 ? w2 : w3;
    bf16* out = wt + (size_t)blockIdx.z * CDIM * CDIM;
    __shared__ bf16 tile[64][65];
    const int t = threadIdx.x;
    const int r0 = blockIdx.x * 64, c0 = blockIdx.y * 64;
    const int r = t >> 2, cc = (t & 3) * 16;
    const float4* src = reinterpret_cast<const float4*>(w + (size_t)(r0 + r) * CDIM + c0 + cc);
#pragma unroll
    for (int v = 0; v < 4; ++v) {
        float4 f = src[v];
        tile[r][cc + v * 4 + 0] = (bf16)f.x;
        tile[r][cc + v * 4 + 1] = (bf16)f.y;
        tile[r][cc + v * 4 + 2] = (bf16)f.z;
        tile[r][cc + v * 4 + 3] = (bf16)f.w;
    }
    __syncthreads();
    bf16x8 o0, o1;
#pragma unroll
    for (int j = 0; j < 8; ++j) { o0[j] = tile[cc + j][r]; o1[j] = tile[cc + 8 + j][r]; }
    bf16* dst = out + (size_t)(c0 + r) * CDIM + r0 + cc;
    *reinterpret_cast<bf16x8*>(dst) = o0;
    *reinterpret_cast<bf16x8*>(dst + 8) = o1;
}

// ---------------------------------------------------------------------------
// 3) QKV GEMM, glds staging, non-swapped mfma -> coalesced row-major stores.
//    Outputs Q,K,V all as [bh][s][64] bf16.
__global__ __launch_bounds__(256) void k_gemm_qkv(const bf16* __restrict__ A,
                                                  const bf16* __restrict__ Wt,
                                                  bf16* __restrict__ Qg,
                                                  bf16* __restrict__ Kg,
                                                  bf16* __restrict__ Vg) {
    __shared__ __align__(16) bf16 As[2][4096];
    __shared__ __align__(16) bf16 Bs[2][4096];
    const int id = blockIdx.x;
    const int swz = (id & 7) * 96 + (id >> 3);           // 768 blocks, bijective
    const int mt = swz & 63, r2 = swz >> 6;
    const int nt = r2 & 3, z = r2 >> 2;
    const int m0 = mt * 128, n0 = nt * 128;
    const int t = threadIdx.x, lane = t & 63, wid = t >> 6;
    const int wr = wid >> 1, wc = wid & 1;
    const int q = lane & 15, g = lane >> 4;
    const bf16* Bmat = Wt + (size_t)z * 262144;
    const int srow = lane >> 2, scol = (lane & 3) * 8;

    auto stage = [&](int buf, int kt) {
        const int k0 = kt * 32;
        const bf16* a0 = A + (size_t)(m0 + wid * 32 + srow) * CDIM + k0 + scol;
        glds16(a0,             &As[buf][wid * 1024]);
        glds16(a0 + 16 * CDIM, &As[buf][wid * 1024 + 512]);
        const bf16* b0 = Bmat + (size_t)(n0 + wid * 32 + srow) * CDIM + k0 + scol;
        glds16(b0,             &Bs[buf][wid * 1024]);
        glds16(b0 + 16 * CDIM, &Bs[buf][wid * 1024 + 512]);
    };

    f32x4 acc[4][4] = {};
    stage(0, 0);
    for (int kt = 0; kt < 16; ++kt) {
        const int cur = kt & 1;
        if (kt < 15) { stage(cur ^ 1, kt + 1); wait_vm4(); } else wait_vm0();
        __syncthreads();
        bf16x8 af[4], bfv[4];
#pragma unroll
        for (int m = 0; m < 4; ++m)
            af[m] = *(const bf16x8*)&As[cur][(wr * 64 + m * 16 + q) * 32 + g * 8];
#pragma unroll
        for (int n = 0; n < 4; ++n)
            bfv[n] = *(const bf16x8*)&Bs[cur][(wc * 64 + n * 16 + q) * 32 + g * 8];
#pragma unroll
        for (int m = 0; m < 4; ++m)
#pragma unroll
            for (int n = 0; n < 4; ++n)
                acc[m][n] = __builtin_amdgcn_mfma_f32_16x16x32_bf16(af[m], bfv[n], acc[m][n], 0, 0, 0);
        __syncthreads();
    }
    bf16* outp = z == 0 ? Qg : (z == 1 ? Kg : Vg);
    // C mapping: col = lane&15 (=q), row = g*4 + i  -> consecutive lanes = consecutive cols
#pragma unroll
    for (int m = 0; m < 4; ++m)
#pragma unroll
        for (int i = 0; i < 4; ++i) {
            const int row = m0 + wr * 64 + m * 16 + g * 4 + i;
            const int bb = row >> 11, s = row & 2047;
#pragma unroll
            for (int n = 0; n < 4; ++n) {
                const int col = n0 + wc * 64 + n * 16 + q;
                const size_t bh = (size_t)bb * HEADS + (col >> 6);
                outp[(bh * SEQ + s) * 64 + (col & 63)] = (bf16)acc[m][n][i];
            }
        }
}

// ---------------------------------------------------------------------------
// 4) V transpose: [bh][s][64] -> Vt[bh][d][s]
__global__ __launch_bounds__(256) void k_vtrans(const bf16* __restrict__ V,
                                                bf16* __restrict__ Vt) {
    __shared__ bf16 tile[64][65];
    const int t = threadIdx.x;
    const int s0 = blockIdx.x * 64;
    const size_t bh = blockIdx.y;
    const int r = t >> 2, cc = (t & 3) * 16;
    const bf16x8* src = reinterpret_cast<const bf16x8*>(V + (bh * SEQ + s0 + r) * 64 + cc);
    bf16x8 v0 = src[0], v1 = src[1];
#pragma unroll
    for (int j = 0; j < 8; ++j) { tile[r][cc + j] = v0[j]; tile[r][cc + 8 + j] = v1[j]; }
    __syncthreads();
    bf16x8 o0, o1;
#pragma unroll
    for (int j = 0; j < 8; ++j) { o0[j] = tile[cc + j][r]; o1[j] = tile[cc + 8 + j][r]; }
    bf16* dst = Vt + (bh * 64 + r) * SEQ + s0 + cc;
    *reinterpret_cast<bf16x8*>(dst) = o0;
    *reinterpret_cast<bf16x8*>(dst + 8) = o1;
}

// ---------------------------------------------------------------------------
// 5) Flash attention — barrier-free, LDS-free, all operands in registers.
//    4 independent waves/block, 32 q/wave, KVBLK=64, double-buffered K/V
//    register prefetch. Swapped QK^T (S^T[kv][q] = mfma(K,Q)); softmax with
//    NO max tracking (scores bounded; exp2 direct); PV un-swapped
//    (O[q][d] = mfma(P,V)) for a fully-coalesced epilogue.
__global__ __launch_bounds__(256, 2) void k_attn(const bf16* __restrict__ Qg,
                                                 const bf16* __restrict__ Kg,
                                                 const bf16* __restrict__ Vt,
                                                 bf16* __restrict__ Og) {
    const int phys = blockIdx.x;                 // 512 blocks
    const int bh  = (phys & 7) * 4 + (phys >> 7);    // XCD-local bh
    const int qbl = (phys >> 3) & 15;
    const int tt = threadIdx.x, lane = tt & 63, wid = tt >> 6;
    const int l31 = lane & 31, hi = lane >> 5;
    const int q0 = qbl * 128 + wid * 32;
    const int b = bh >> 3, h = bh & 7;

    bf16x8 qf[4];
    const bf16* Qrow = Qg + ((size_t)bh * SEQ + q0 + l31) * 64 + hi * 8;
#pragma unroll
    for (int kb = 0; kb < 4; ++kb) qf[kb] = *(const bf16x8*)(Qrow + kb * 16);

    const bf16* Kbase = Kg + ((size_t)bh * SEQ + l31) * 64 + hi * 8;
    const bf16* Vbase = Vt + ((size_t)bh * 64 + l31) * SEQ + hi * 8;

    f32x16 oacc0 = {}, oacc1 = {};
    float l0 = 0.f, l1 = 0.f, l2 = 0.f, l3 = 0.f;

    bf16x8 kA[8], vA[8], kB[8], vB[8];

    auto loadkv = [&](bf16x8 (&kf)[8], bf16x8 (&vf)[8], int kv0) {
#pragma unroll
        for (int kt2 = 0; kt2 < 2; ++kt2)
#pragma unroll
            for (int kb = 0; kb < 4; ++kb)
                kf[kt2 * 4 + kb] = *(const bf16x8*)(Kbase + (size_t)(kv0 + kt2 * 32) * 64 + kb * 16);
#pragma unroll
        for (int dt = 0; dt < 2; ++dt)
#pragma unroll
            for (int kvb = 0; kvb < 4; ++kvb)
                vf[dt * 4 + kvb] = *(const bf16x8*)(Vbase + (size_t)dt * 32 * SEQ + kv0 + kvb * 16);
    };

    auto compute = [&](bf16x8 (&kf)[8], bf16x8 (&vf)[8]) {
        f32x16 sa0 = {}, sa1 = {};
        __builtin_amdgcn_s_setprio(1);
#pragma unroll
        for (int kb = 0; kb < 4; ++kb) {
            sa0 = __builtin_amdgcn_mfma_f32_32x32x16_bf16(kf[kb],     qf[kb], sa0, 0, 0, 0);
            sa1 = __builtin_amdgcn_mfma_f32_32x32x16_bf16(kf[4 + kb], qf[kb], sa1, 0, 0, 0);
        }
        __builtin_amdgcn_s_setprio(0);
        // softmax, no max subtraction (scores bounded, f32 range is ample)
        float p0[16], p1[16];
#pragma unroll
        for (int r = 0; r < 16; ++r) { p0[r] = exp2f(sa0[r] * C2); p1[r] = exp2f(sa1[r] * C2); }
#pragma unroll
        for (int r = 0; r < 16; r += 4) {
            l0 += p0[r]     + p1[r];
            l1 += p0[r + 1] + p1[r + 1];
            l2 += p0[r + 2] + p1[r + 2];
            l3 += p0[r + 3] + p1[r + 3];
        }
        // pack P -> A-frags (rows=q) via cvt_pk + permlane32_swap
        bf16x8 pa[4];
#pragma unroll
        for (int kvb = 0; kvb < 4; ++kvb) {
            const float* S = (kvb < 2) ? p0 : p1;
            const int b0 = (kvb & 1) * 8;
            uint32_t a0 = pk_bf16(S[b0],     S[b0 + 1]);
            uint32_t c0 = pk_bf16(S[b0 + 4], S[b0 + 5]);
            uint32_t a1 = pk_bf16(S[b0 + 2], S[b0 + 3]);
            uint32_t c1 = pk_bf16(S[b0 + 6], S[b0 + 7]);
            pl_swap(a0, c0); pl_swap(a1, c1);
            union { uint32_t w[4]; bf16x8 v; } u;
            u.w[0] = a0; u.w[1] = a1; u.w[2] = c0; u.w[3] = c1;
            pa[kvb] = u.v;
        }
        __builtin_amdgcn_s_setprio(1);
#pragma unroll
        for (int kvb = 0; kvb < 4; ++kvb) {
            oacc0 = __builtin_amdgcn_mfma_f32_32x32x16_bf16(pa[kvb], vf[kvb],     oacc0, 0, 0, 0);
            oacc1 = __builtin_amdgcn_mfma_f32_32x32x16_bf16(pa[kvb], vf[4 + kvb], oacc1, 0, 0, 0);
        }
        __builtin_amdgcn_s_setprio(0);
    };

    loadkv(kA, vA, 0);
    for (int t = 0; t < 32; t += 2) {
        loadkv(kB, vB, (t + 1) * 64);
        compute(kA, vA);
        if (t + 2 < 32) loadkv(kA, vA, (t + 2) * 64);
        compute(kB, vB);
    }

    float lsum = (l0 + l1) + (l2 + l3);
    lsum += __shfl_xor(lsum, 32);
    const float inv = 1.0f / lsum;
    // oacc: col = d (lane&31), rows q = (r&3)+8*(r>>2)+4*hi
    bf16* orow = Og + ((size_t)b * SEQ + q0) * CDIM + h * 64 + l31;
#pragma unroll
    for (int r = 0; r < 16; ++r) {
        const int qrow = (r & 3) + 8 * (r >> 2) + 4 * hi;
        const float invr = __shfl(inv, qrow);
        orow[(size_t)qrow * CDIM]      = (bf16)(oacc0[r] * invr);
        orow[(size_t)qrow * CDIM + 32] = (bf16)(oacc1[r] * invr);
    }
}

// ---------------------------------------------------------------------------
// 6) Output GEMM: Og[8192][512]bf16 x WoT[512][512]bf16 -> out f32.
//    128x64 tiles, glds staging, non-swapped mfma, coalesced f32 stores.
__global__ __launch_bounds__(256) void k_gemm_o(const bf16* __restrict__ A,
                                                const bf16* __restrict__ Bt,
                                                float* __restrict__ out) {
    __shared__ __align__(16) bf16 As[2][4096];
    __shared__ __align__(16) bf16 Bs[2][2048];
    const int id = blockIdx.x;
    const int swz = (id & 7) * 64 + (id >> 3);       // 512 blocks, bijective
    const int mt = swz & 63, nt = swz >> 6;
    const int m0 = mt * 128, n0 = nt * 64;
    const int t = threadIdx.x, lane = t & 63, wid = t >> 6;
    const int wr = wid >> 1, wc = wid & 1;
    const int q = lane & 15, g = lane >> 4;
    const int srow = lane >> 2, scol = (lane & 3) * 8;

    auto stage = [&](int buf, int kt) {
        const int k0 = kt * 32;
        const bf16* a0 = A + (size_t)(m0 + wid * 32 + srow) * CDIM + k0 + scol;
        glds16(a0,             &As[buf][wid * 1024]);
        glds16(a0 + 16 * CDIM, &As[buf][wid * 1024 + 512]);
        const bf16* b0 = Bt + (size_t)(n0 + wid * 16 + srow) * CDIM + k0 + scol;
        glds16(b0, &Bs[buf][wid * 512]);
    };

    f32x4 acc[4][2] = {};
    stage(0, 0);
    for (int kt = 0; kt < 16; ++kt) {
        const int cur = kt & 1;
        if (kt < 15) { stage(cur ^ 1, kt + 1); wait_vm3(); } else wait_vm0();
        __syncthreads();
        bf16x8 af[4], bfv[2];
#pragma unroll
        for (int m = 0; m < 4; ++m)
            af[m] = *(const bf16x8*)&As[cur][(wr * 64 + m * 16 + q) * 32 + g * 8];
#pragma unroll
        for (int n = 0; n < 2; ++n)
            bfv[n] = *(const bf16x8*)&Bs[cur][(wc * 32 + n * 16 + q) * 32 + g * 8];
#pragma unroll
        for (int m = 0; m < 4; ++m)
#pragma unroll
            for (int n = 0; n < 2; ++n)
                acc[m][n] = __builtin_amdgcn_mfma_f32_16x16x32_bf16(af[m], bfv[n], acc[m][n], 0, 0, 0);
        __syncthreads();
    }
#pragma unroll
    for (int m = 0; m < 4; ++m)
#pragma unroll
        for (int n = 0; n < 2; ++n)
#pragma unroll
            for (int i = 0; i < 4; ++i) {
                const int row = m0 + wr * 64 + m * 16 + g * 4 + i;
                const int col = n0 + wc * 32 + n * 16 + q;
                out[(size_t)row * CDIM + col] = acc[m][n][i];
            }
}

// ---------------------------------------------------------------------------
extern "C" void kernel_launch(void* const* d_in, const int* in_sizes, int n_in,
                              void* d_out, int out_size, void* d_ws, size_t ws_size,
                              hipStream_t stream) {
    const float* hs = (const float*)d_in[0];
    const float* Wq = (const float*)d_in[1];
    const float* Wk = (const float*)d_in[2];
    const float* Wv = (const float*)d_in[3];
    const float* Wo = (const float*)d_in[4];
    float* out = (float*)d_out;

    bf16* hs_bf = (bf16*)d_ws;                 //  8 MB  (8192x512)
    bf16* wt    = hs_bf + 4194304;             //  2 MB  (4 x 512x512, [fout][fin])
    bf16* Qg    = wt + 1048576;                //  8 MB  [bh][s][64]
    bf16* Kg    = Qg + 4194304;                //  8 MB  [bh][s][64]
    bf16* Vg    = Kg + 4194304;                //  8 MB  [bh][s][64]
    bf16* Vt    = Vg + 4194304;                //  8 MB  [bh][d][s]
    bf16* Og    = Vt + 4194304;                //  8 MB  [b][s][512]

    k_cvt_hs<<<2048, 256, 0, stream>>>(hs, hs_bf);
    k_wtrans<<<dim3(8, 8, 4), 256, 0, stream>>>(Wq, Wk, Wv, Wo, wt);
    k_gemm_qkv<<<768, 256, 0, stream>>>(hs_bf, wt, Qg, Kg, Vg);
    k_vtrans<<<dim3(32, 32), 256, 0, stream>>>(Vg, Vt);
    k_attn<<<512, 256, 0, stream>>>(Qg, Kg, Vt, Og);
    k_gemm_o<<<512, 256, 0, stream>>>(Og, wt + 3 * 262144, out);
}

// Round 12
// 180.481 us; speedup vs baseline: 1.3124x; 1.3124x over previous
//
#include <hip/hip_runtime.h>
#include <hip/hip_bf16.h>
#include <stdint.h>

typedef __bf16 bf16;
typedef __attribute__((ext_vector_type(8))) __bf16 bf16x8;
typedef __attribute__((ext_vector_type(4))) float f32x4;
typedef __attribute__((ext_vector_type(16))) float f32x16;

#define SEQ   2048
#define HEADS 8
#define CDIM  512
// C2 = SCALE * log2(e) = 0.125 * 1.4426950408889634
#define C2 0.18033688011112043f

__device__ __forceinline__ void glds16(const bf16* g, bf16* l) {
    __builtin_amdgcn_global_load_lds((const __attribute__((address_space(1))) void*)g,
                                     (__attribute__((address_space(3))) void*)l, 16, 0, 0);
}
__device__ __forceinline__ uint32_t pk_bf16(float a, float b) {
    uint32_t r; asm("v_cvt_pk_bf16_f32 %0, %1, %2" : "=v"(r) : "v"(a), "v"(b)); return r;
}
__device__ __forceinline__ void pl_swap(uint32_t &a, uint32_t &b) {
    asm("v_permlane32_swap_b32 %0, %1" : "+v"(a), "+v"(b));
}
__device__ __forceinline__ void wait_vm4() { asm volatile("s_waitcnt vmcnt(4)" ::: "memory"); }
__device__ __forceinline__ void wait_vm3() { asm volatile("s_waitcnt vmcnt(3)" ::: "memory"); }
__device__ __forceinline__ void wait_vm0() { asm volatile("s_waitcnt vmcnt(0)" ::: "memory"); }

// ---------------------------------------------------------------------------
// 1) hs fp32 -> bf16
__global__ __launch_bounds__(256) void k_cvt_hs(const float* __restrict__ in,
                                                bf16* __restrict__ out) {
    int idx = blockIdx.x * 256 + threadIdx.x;
    const float4* in4 = reinterpret_cast<const float4*>(in);
    float4 a = in4[idx * 2], b = in4[idx * 2 + 1];
    bf16x8 o;
    o[0] = (bf16)a.x; o[1] = (bf16)a.y; o[2] = (bf16)a.z; o[3] = (bf16)a.w;
    o[4] = (bf16)b.x; o[5] = (bf16)b.y; o[6] = (bf16)b.z; o[7] = (bf16)b.w;
    reinterpret_cast<bf16x8*>(out)[idx] = o;
}

// ---------------------------------------------------------------------------
// 2) weight transpose+convert: W[fin][fout] f32 -> Wt[fout][fin] bf16 (4 mats)
__global__ __launch_bounds__(256) void k_wtrans(const float* __restrict__ w0,
                                                const float* __restrict__ w1,
                                                const float* __restrict__ w2,
                                                const float* __restrict__ w3,
                                                bf16* __restrict__ wt) {
    const float* w = blockIdx.z == 0 ? w0 : blockIdx.z == 1 ? w1 : blockIdx.z == 2 ? w2 : w3;
    bf16* out = wt + (size_t)blockIdx.z * CDIM * CDIM;
    __shared__ bf16 tile[64][65];
    const int t = threadIdx.x;
    const int r0 = blockIdx.x * 64, c0 = blockIdx.y * 64;
    const int r = t >> 2, cc = (t & 3) * 16;
    const float4* src = reinterpret_cast<const float4*>(w + (size_t)(r0 + r) * CDIM + c0 + cc);
#pragma unroll
    for (int v = 0; v < 4; ++v) {
        float4 f = src[v];
        tile[r][cc + v * 4 + 0] = (bf16)f.x;
        tile[r][cc + v * 4 + 1] = (bf16)f.y;
        tile[r][cc + v * 4 + 2] = (bf16)f.z;
        tile[r][cc + v * 4 + 3] = (bf16)f.w;
    }
    __syncthreads();
    bf16x8 o0, o1;
#pragma unroll
    for (int j = 0; j < 8; ++j) { o0[j] = tile[cc + j][r]; o1[j] = tile[cc + 8 + j][r]; }
    bf16* dst = out + (size_t)(c0 + r) * CDIM + r0 + cc;
    *reinterpret_cast<bf16x8*>(dst) = o0;
    *reinterpret_cast<bf16x8*>(dst + 8) = o1;
}

// ---------------------------------------------------------------------------
// 3) QKV GEMM, glds staging. Q row-major [bh][s][64]; K,V in attention
//    FRAGMENT order (per (bh, 64-kv tile), 4096 bf16):
//      K (s,d): ((kt2*4+kb)*64 + hk*32 + (s&31))*8 + (d&7),
//               kt2=(s>>5)&1, kb=(d&63)>>4, hk=(d>>3)&1
//      V (s,d): ((dt*4+kvb)*64 + hh*32 + (d&31))*8 + (s&7),
//               dt=(d&63)>>5, kvb=(s>>4)&3, hh=(s>>3)&1
__global__ __launch_bounds__(256) void k_gemm_qkv(const bf16* __restrict__ A,
                                                  const bf16* __restrict__ Wt,
                                                  bf16* __restrict__ Qg,
                                                  bf16* __restrict__ Kf,
                                                  bf16* __restrict__ Vf) {
    __shared__ __align__(16) bf16 As[2][4096];
    __shared__ __align__(16) bf16 Bs[2][4096];
    const int id = blockIdx.x;
    const int swz = (id & 7) * 96 + (id >> 3);           // 768 blocks, bijective
    const int mt = swz & 63, r2 = swz >> 6;
    const int nt = r2 & 3, z = r2 >> 2;
    const int m0 = mt * 128, n0 = nt * 128;
    const int t = threadIdx.x, lane = t & 63, wid = t >> 6;
    const int wr = wid >> 1, wc = wid & 1;
    const int q = lane & 15, g = lane >> 4;
    const bf16* Bmat = Wt + (size_t)z * 262144;
    const int srow = lane >> 2, scol = (lane & 3) * 8;

    auto stage = [&](int buf, int kt) {
        const int k0 = kt * 32;
        const bf16* a0 = A + (size_t)(m0 + wid * 32 + srow) * CDIM + k0 + scol;
        glds16(a0,             &As[buf][wid * 1024]);
        glds16(a0 + 16 * CDIM, &As[buf][wid * 1024 + 512]);
        const bf16* b0 = Bmat + (size_t)(n0 + wid * 32 + srow) * CDIM + k0 + scol;
        glds16(b0,             &Bs[buf][wid * 1024]);
        glds16(b0 + 16 * CDIM, &Bs[buf][wid * 1024 + 512]);
    };

    f32x4 acc[4][4] = {};
    stage(0, 0);
    for (int kt = 0; kt < 16; ++kt) {
        const int cur = kt & 1;
        if (kt < 15) { stage(cur ^ 1, kt + 1); wait_vm4(); } else wait_vm0();
        __syncthreads();
        bf16x8 af[4], bfv[4];
#pragma unroll
        for (int m = 0; m < 4; ++m)
            af[m] = *(const bf16x8*)&As[cur][(wr * 64 + m * 16 + q) * 32 + g * 8];
#pragma unroll
        for (int n = 0; n < 4; ++n)
            bfv[n] = *(const bf16x8*)&Bs[cur][(wc * 64 + n * 16 + q) * 32 + g * 8];
#pragma unroll
        for (int m = 0; m < 4; ++m)
#pragma unroll
            for (int n = 0; n < 4; ++n)
                acc[m][n] = __builtin_amdgcn_mfma_f32_16x16x32_bf16(af[m], bfv[n], acc[m][n], 0, 0, 0);
        __syncthreads();
    }
    // C mapping: col = lane&15 (=q), row = g*4 + i
#pragma unroll
    for (int m = 0; m < 4; ++m) {
        if (z == 2) {                                   // V: 4 consecutive s -> uint2
            const int s0r = m0 + wr * 64 + m * 16 + g * 4;
            const int bb = s0r >> 11, s0 = s0r & 2047;
            const int tile = s0 >> 6, kvb = (s0 >> 4) & 3, hh = (s0 >> 3) & 1, j0 = s0 & 7;
#pragma unroll
            for (int n = 0; n < 4; ++n) {
                const int col = n0 + wc * 64 + n * 16 + q;
                const size_t bh = (size_t)bb * HEADS + (col >> 6);
                const int d0 = col & 63, dt = d0 >> 5, lv = d0 & 31;
                uint2 u;
                u.x = pk_bf16(acc[m][n][0], acc[m][n][1]);
                u.y = pk_bf16(acc[m][n][2], acc[m][n][3]);
                *(uint2*)&Vf[(bh * 32 + tile) * 4096 +
                             (size_t)(((dt * 4 + kvb) * 64 + hh * 32 + lv) * 8 + j0)] = u;
            }
        } else if (z == 1) {                            // K: scalar stores
#pragma unroll
            for (int i = 0; i < 4; ++i) {
                const int row = m0 + wr * 64 + m * 16 + g * 4 + i;
                const int bb = row >> 11, s = row & 2047;
                const int tile = s >> 6, kt2 = (s >> 5) & 1, ls = s & 31;
#pragma unroll
                for (int n = 0; n < 4; ++n) {
                    const int col = n0 + wc * 64 + n * 16 + q;
                    const size_t bh = (size_t)bb * HEADS + (col >> 6);
                    const int d0 = col & 63, kb = d0 >> 4, hk = (d0 >> 3) & 1, j = d0 & 7;
                    Kf[(bh * 32 + tile) * 4096 +
                       (size_t)(((kt2 * 4 + kb) * 64 + hk * 32 + ls) * 8 + j)] = (bf16)acc[m][n][i];
                }
            }
        } else {                                        // Q row-major
#pragma unroll
            for (int i = 0; i < 4; ++i) {
                const int row = m0 + wr * 64 + m * 16 + g * 4 + i;
                const int bb = row >> 11, s = row & 2047;
#pragma unroll
                for (int n = 0; n < 4; ++n) {
                    const int col = n0 + wc * 64 + n * 16 + q;
                    const size_t bh = (size_t)bb * HEADS + (col >> 6);
                    Qg[(bh * SEQ + s) * 64 + (col & 63)] = (bf16)acc[m][n][i];
                }
            }
        }
    }
}

// ---------------------------------------------------------------------------
// 4) Flash attention, KV-split 2-way. LDS frag-order staging via glds16,
//    double-buffered, vmcnt(4) (round-2 measured structure). No-max exp2
//    softmax (partials combine linearly), swapped QK^T, in-reg P pack,
//    un-swapped PV. f32 partial O + l to workspace; merged by k_merge.
//    1024 blocks = 4 blocks/CU -> 16 waves/CU.
__global__ __launch_bounds__(256, 4) void k_attn(const bf16* __restrict__ Qg,
                                                 const bf16* __restrict__ Kf,
                                                 const bf16* __restrict__ Vf,
                                                 float* __restrict__ Op,
                                                 float* __restrict__ Lp) {
    __shared__ __align__(16) bf16 KV[2][2][4096];   // [buf][K/V][frag order]
    const int id = blockIdx.x;                       // 1024
    const int swz = (id & 7) * 128 + (id >> 3);      // bijective; 4 heads per XCD
    const int bh = swz >> 5;
    const int chunk = (swz >> 4) & 1;
    const int qb = swz & 15;
    const int tt = threadIdx.x, lane = tt & 63, wid = tt >> 6;
    const int l31 = lane & 31, hi = lane >> 5;
    const int q0 = qb * 128 + wid * 32;

    bf16x8 qf[4];
    const bf16* Qrow = Qg + ((size_t)bh * SEQ + q0 + l31) * 64 + hi * 8;
#pragma unroll
    for (int kb = 0; kb < 4; ++kb) qf[kb] = *(const bf16x8*)(Qrow + kb * 16);

    f32x16 oacc0 = {}, oacc1 = {};
    float l0 = 0.f, l1 = 0.f, l2 = 0.f, l3 = 0.f;

    auto stage = [&](int buf, int gt) {
        const bf16* kb_ = Kf + ((size_t)bh * 32 + gt) * 4096;
        const bf16* vb_ = Vf + ((size_t)bh * 32 + gt) * 4096;
        const int g0 = wid * 2;
        glds16(kb_ + g0 * 512 + lane * 8,       &KV[buf][0][g0 * 512]);
        glds16(kb_ + (g0 + 1) * 512 + lane * 8, &KV[buf][0][(g0 + 1) * 512]);
        glds16(vb_ + g0 * 512 + lane * 8,       &KV[buf][1][g0 * 512]);
        glds16(vb_ + (g0 + 1) * 512 + lane * 8, &KV[buf][1][(g0 + 1) * 512]);
    };

    const int t0 = chunk * 16;
    stage(0, t0);
    for (int kt = 0; kt < 16; ++kt) {
        const int cur = kt & 1;
        if (kt < 15) { stage(cur ^ 1, t0 + kt + 1); wait_vm4(); } else wait_vm0();
        __syncthreads();

        // --- QK^T (swapped): sa col = q (lane&31), rows = kv slots ---
        f32x16 sa0 = {}, sa1 = {};
        __builtin_amdgcn_s_setprio(1);
#pragma unroll
        for (int kb = 0; kb < 4; ++kb) {
            bf16x8 k0 = *(const bf16x8*)&KV[cur][0][((0 * 4 + kb) * 64 + lane) * 8];
            bf16x8 k1 = *(const bf16x8*)&KV[cur][0][((1 * 4 + kb) * 64 + lane) * 8];
            sa0 = __builtin_amdgcn_mfma_f32_32x32x16_bf16(k0, qf[kb], sa0, 0, 0, 0);
            sa1 = __builtin_amdgcn_mfma_f32_32x32x16_bf16(k1, qf[kb], sa1, 0, 0, 0);
        }
        __builtin_amdgcn_s_setprio(0);

        // --- no-max softmax (scores bounded; f32 range ample) ---
        float p0[16], p1[16];
#pragma unroll
        for (int r = 0; r < 16; ++r) { p0[r] = exp2f(sa0[r] * C2); p1[r] = exp2f(sa1[r] * C2); }
#pragma unroll
        for (int r = 0; r < 16; r += 4) {
            l0 += p0[r]     + p1[r];
            l1 += p0[r + 1] + p1[r + 1];
            l2 += p0[r + 2] + p1[r + 2];
            l3 += p0[r + 3] + p1[r + 3];
        }
        // --- pack P -> A-frags (rows=q) via cvt_pk + permlane32_swap ---
        bf16x8 pa[4];
#pragma unroll
        for (int kvb = 0; kvb < 4; ++kvb) {
            const float* S = (kvb < 2) ? p0 : p1;
            const int b0 = (kvb & 1) * 8;
            uint32_t a0 = pk_bf16(S[b0],     S[b0 + 1]);
            uint32_t c0 = pk_bf16(S[b0 + 4], S[b0 + 5]);
            uint32_t a1 = pk_bf16(S[b0 + 2], S[b0 + 3]);
            uint32_t c1 = pk_bf16(S[b0 + 6], S[b0 + 7]);
            pl_swap(a0, c0); pl_swap(a1, c1);
            union { uint32_t w[4]; bf16x8 v; } u;
            u.w[0] = a0; u.w[1] = a1; u.w[2] = c0; u.w[3] = c1;
            pa[kvb] = u.v;
        }
        // --- PV (un-swapped): O[q][d], col = d (lane&31) ---
        __builtin_amdgcn_s_setprio(1);
#pragma unroll
        for (int kvb = 0; kvb < 4; ++kvb) {
            bf16x8 v0 = *(const bf16x8*)&KV[cur][1][((0 * 4 + kvb) * 64 + lane) * 8];
            bf16x8 v1 = *(const bf16x8*)&KV[cur][1][((1 * 4 + kvb) * 64 + lane) * 8];
            oacc0 = __builtin_amdgcn_mfma_f32_32x32x16_bf16(pa[kvb], v0, oacc0, 0, 0, 0);
            oacc1 = __builtin_amdgcn_mfma_f32_32x32x16_bf16(pa[kvb], v1, oacc1, 0, 0, 0);
        }
        __builtin_amdgcn_s_setprio(0);
        __syncthreads();
    }

    float lsum = (l0 + l1) + (l2 + l3);
    lsum += __shfl_xor(lsum, 32);
    float* obase = Op + (((size_t)chunk * 32 + bh) * 2048 + q0) * 64;
#pragma unroll
    for (int r = 0; r < 16; ++r) {
        const int qrow = (r & 3) + 8 * (r >> 2) + 4 * hi;
        obase[(size_t)qrow * 64 + l31]      = oacc0[r];
        obase[(size_t)qrow * 64 + 32 + l31] = oacc1[r];
    }
    if (hi == 0) Lp[((size_t)chunk * 32 + bh) * 2048 + q0 + l31] = lsum;
}

// ---------------------------------------------------------------------------
// 5) Merge partials: Og = (O0+O1)/(l0+l1), write [b][s][512] bf16
__global__ __launch_bounds__(256) void k_merge(const float* __restrict__ Op,
                                               const float* __restrict__ Lp,
                                               bf16* __restrict__ Og) {
    const int blk = blockIdx.x;                // 2048
    const int t = threadIdx.x;
    const int row = blk * 32 + (t >> 3);       // 65536 rows (bh*2048+q)
    const int d0 = (t & 7) * 8;
    const int bh = row >> 11, q = row & 2047;
    const int b = bh >> 3, h = bh & 7;
    const float* o0 = Op + (size_t)row * 64 + d0;
    const float* o1 = o0 + (size_t)65536 * 64;
    const float inv = 1.0f / (Lp[row] + Lp[65536 + row]);
    float4 a0 = ((const float4*)o0)[0], a1 = ((const float4*)o0)[1];
    float4 b0 = ((const float4*)o1)[0], b1 = ((const float4*)o1)[1];
    bf16x8 o;
    o[0] = (bf16)((a0.x + b0.x) * inv); o[1] = (bf16)((a0.y + b0.y) * inv);
    o[2] = (bf16)((a0.z + b0.z) * inv); o[3] = (bf16)((a0.w + b0.w) * inv);
    o[4] = (bf16)((a1.x + b1.x) * inv); o[5] = (bf16)((a1.y + b1.y) * inv);
    o[6] = (bf16)((a1.z + b1.z) * inv); o[7] = (bf16)((a1.w + b1.w) * inv);
    *(bf16x8*)&Og[((size_t)b * SEQ + q) * CDIM + h * 64 + d0] = o;
}

// ---------------------------------------------------------------------------
// 6) Output GEMM: Og[8192][512]bf16 x WoT[512][512]bf16 -> out f32.
__global__ __launch_bounds__(256) void k_gemm_o(const bf16* __restrict__ A,
                                                const bf16* __restrict__ Bt,
                                                float* __restrict__ out) {
    __shared__ __align__(16) bf16 As[2][4096];
    __shared__ __align__(16) bf16 Bs[2][2048];
    const int id = blockIdx.x;
    const int swz = (id & 7) * 64 + (id >> 3);       // 512 blocks, bijective
    const int mt = swz & 63, nt = swz >> 6;
    const int m0 = mt * 128, n0 = nt * 64;
    const int t = threadIdx.x, lane = t & 63, wid = t >> 6;
    const int wr = wid >> 1, wc = wid & 1;
    const int q = lane & 15, g = lane >> 4;
    const int srow = lane >> 2, scol = (lane & 3) * 8;

    auto stage = [&](int buf, int kt) {
        const int k0 = kt * 32;
        const bf16* a0 = A + (size_t)(m0 + wid * 32 + srow) * CDIM + k0 + scol;
        glds16(a0,             &As[buf][wid * 1024]);
        glds16(a0 + 16 * CDIM, &As[buf][wid * 1024 + 512]);
        const bf16* b0 = Bt + (size_t)(n0 + wid * 16 + srow) * CDIM + k0 + scol;
        glds16(b0, &Bs[buf][wid * 512]);
    };

    f32x4 acc[4][2] = {};
    stage(0, 0);
    for (int kt = 0; kt < 16; ++kt) {
        const int cur = kt & 1;
        if (kt < 15) { stage(cur ^ 1, kt + 1); wait_vm3(); } else wait_vm0();
        __syncthreads();
        bf16x8 af[4], bfv[2];
#pragma unroll
        for (int m = 0; m < 4; ++m)
            af[m] = *(const bf16x8*)&As[cur][(wr * 64 + m * 16 + q) * 32 + g * 8];
#pragma unroll
        for (int n = 0; n < 2; ++n)
            bfv[n] = *(const bf16x8*)&Bs[cur][(wc * 32 + n * 16 + q) * 32 + g * 8];
#pragma unroll
        for (int m = 0; m < 4; ++m)
#pragma unroll
            for (int n = 0; n < 2; ++n)
                acc[m][n] = __builtin_amdgcn_mfma_f32_16x16x32_bf16(af[m], bfv[n], acc[m][n], 0, 0, 0);
        __syncthreads();
    }
#pragma unroll
    for (int m = 0; m < 4; ++m)
#pragma unroll
        for (int n = 0; n < 2; ++n)
#pragma unroll
            for (int i = 0; i < 4; ++i) {
                const int row = m0 + wr * 64 + m * 16 + g * 4 + i;
                const int col = n0 + wc * 32 + n * 16 + q;
                out[(size_t)row * CDIM + col] = acc[m][n][i];
            }
}

// ---------------------------------------------------------------------------
extern "C" void kernel_launch(void* const* d_in, const int* in_sizes, int n_in,
                              void* d_out, int out_size, void* d_ws, size_t ws_size,
                              hipStream_t stream) {
    const float* hs = (const float*)d_in[0];
    const float* Wq = (const float*)d_in[1];
    const float* Wk = (const float*)d_in[2];
    const float* Wv = (const float*)d_in[3];
    const float* Wo = (const float*)d_in[4];
    float* out = (float*)d_out;

    bf16* hs_bf = (bf16*)d_ws;                 //  8 MB
    bf16* wt    = hs_bf + 4194304;             //  2 MB
    bf16* Qg    = wt + 1048576;                //  8 MB [bh][s][64]
    bf16* Kf    = Qg + 4194304;                //  8 MB frag-order
    bf16* Vf    = Kf + 4194304;                //  8 MB frag-order
    bf16* Og    = Vf + 4194304;                //  8 MB [b][s][512]
    float* Op   = (float*)(Og + 4194304);      // 32 MB f32 partials [2][32][2048][64]
    float* Lp   = Op + (size_t)2 * 65536 * 64; // 0.5 MB f32 [2][65536]

    k_cvt_hs<<<2048, 256, 0, stream>>>(hs, hs_bf);
    k_wtrans<<<dim3(8, 8, 4), 256, 0, stream>>>(Wq, Wk, Wv, Wo, wt);
    k_gemm_qkv<<<768, 256, 0, stream>>>(hs_bf, wt, Qg, Kf, Vf);
    k_attn<<<1024, 256, 0, stream>>>(Qg, Kf, Vf, Op, Lp);
    k_merge<<<2048, 256, 0, stream>>>(Op, Lp, Og);
    k_gemm_o<<<512, 256, 0, stream>>>(Og, wt + 3 * 262144, out);
}